// Round 2
// baseline (198.104 us; speedup 1.0000x reference)
//
#include <hip/hip_runtime.h>

// ---------------------------------------------------------------------------
// ConvFeatureExtractor: profile = rownorm( freq @ softmax(matches/T, axis=1)^T )
//   matches[f,i] = sum_j kmer_params[f, digit_j(i), j],  F=8192, M=4096, B=1024, K=6
// Plan:
//   k1: cast freq (1024x4096 f32) -> bf16        (ws)
//   k2: per-filter matches + softmax -> probs bf16 (8192x4096, ws)
//   k3: MFMA GEMM pooled = freq_bf16 @ probs^T -> d_out f32 (1024x8192)
//   k4: row-normalize d_out in place
// ---------------------------------------------------------------------------

typedef __bf16  bf16x8 __attribute__((ext_vector_type(8)));
typedef float   f32x4  __attribute__((ext_vector_type(4)));

#define GLD16(gp, lp)                                                          \
  __builtin_amdgcn_global_load_lds(                                            \
      (const __attribute__((address_space(1))) void*)(gp),                     \
      (__attribute__((address_space(3))) void*)(lp), 16, 0, 0)

__device__ __forceinline__ short f2bf(float x) {
  unsigned u = __float_as_uint(x);
  unsigned r = (u + 0x7fffu + ((u >> 16) & 1u)) >> 16;   // RNE
  return (short)r;
}

__device__ __forceinline__ float wave_max(float v) {
  #pragma unroll
  for (int off = 32; off; off >>= 1) v = fmaxf(v, __shfl_xor(v, off, 64));
  return v;
}
__device__ __forceinline__ float wave_sum(float v) {
  #pragma unroll
  for (int off = 32; off; off >>= 1) v += __shfl_xor(v, off, 64);
  return v;
}

// ---------------- k1: freq f32 -> bf16 ----------------
__global__ __launch_bounds__(256) void cast_kernel(const float* __restrict__ in,
                                                   short* __restrict__ out) {
  int idx = blockIdx.x * 256 + threadIdx.x;      // 1048576 threads, 4 floats each
  float4 v = ((const float4*)in)[idx];
  short4 o;
  o.x = f2bf(v.x); o.y = f2bf(v.y); o.z = f2bf(v.z); o.w = f2bf(v.w);
  ((short4*)out)[idx] = o;
}

// ---------------- k2: matches + softmax -> probs bf16 ----------------
// grid = 8192 (one block per filter), block = 256
__global__ __launch_bounds__(256) void probs_kernel(const float* __restrict__ kp,
                                                    const float* __restrict__ temp,
                                                    short* __restrict__ probs) {
  const int f = blockIdx.x;
  const int t = threadIdx.x;
  const int lane = t & 63, wave = t >> 6;

  __shared__ float P[24];          // kmer_params[f] : [4][6]
  __shared__ float Thi[64], Tlo[64];
  __shared__ float redA[4], redB[4];

  if (t < 24) P[t] = kp[f * 24 + t];
  __syncthreads();
  if (t < 64) {
    // digits most-significant first: Thi covers j=0,1,2 ; Tlo covers j=3,4,5
    Thi[t] = P[((t >> 4) & 3) * 6 + 0] + P[((t >> 2) & 3) * 6 + 1] + P[(t & 3) * 6 + 2];
    Tlo[t] = P[((t >> 4) & 3) * 6 + 3] + P[((t >> 2) & 3) * 6 + 4] + P[(t & 3) * 6 + 5];
  }
  __syncthreads();

  float m[16];
  float mx = -1e30f;
  #pragma unroll
  for (int s = 0; s < 16; s++) {
    int i = s * 256 + t;
    m[s] = Thi[i >> 6] + Tlo[i & 63];
    mx = fmaxf(mx, m[s]);
  }
  float wmx = wave_max(mx);
  if (lane == 0) redA[wave] = wmx;
  __syncthreads();
  mx = fmaxf(fmaxf(redA[0], redA[1]), fmaxf(redA[2], redA[3]));

  const float invT = 1.0f / temp[0];
  float e[16];
  float lsum = 0.0f;
  #pragma unroll
  for (int s = 0; s < 16; s++) {
    e[s] = __expf((m[s] - mx) * invT);
    lsum += e[s];
  }
  float wsum = wave_sum(lsum);
  if (lane == 0) redB[wave] = wsum;
  __syncthreads();
  float tot = (redB[0] + redB[1]) + (redB[2] + redB[3]);
  float inv = 1.0f / tot;

  short* prow = probs + f * 4096;
  #pragma unroll
  for (int s = 0; s < 16; s++) prow[s * 256 + t] = f2bf(e[s] * inv);
}

// ---------------- k3: GEMM pooled = A(1024x4096) * B(8192x4096)^T ----------------
// C row-major 1024x8192 fp32. Tiles: TM=128 (batch), TN=128 (filters), BK=64.
// 256 threads = 4 waves in 2x2; each wave does 64x64 via 4x4 of 16x16x32 mfma.
__global__ __launch_bounds__(256) void gemm_kernel(const short* __restrict__ A,
                                                   const short* __restrict__ Bm,
                                                   float* __restrict__ C) {
  __shared__ short As[128 * 64];
  __shared__ short Bs[128 * 64];

  const int t = threadIdx.x;
  const int lane = t & 63, wave = t >> 6;
  const int quad = lane >> 4, l16 = lane & 15;
  const int m0 = blockIdx.y * 128;       // batch tile
  const int n0 = blockIdx.x * 128;       // filter tile
  const int wm = (wave & 1) * 64, wn = (wave >> 1) * 64;

  f32x4 acc[4][4];
  #pragma unroll
  for (int i = 0; i < 4; i++)
    #pragma unroll
    for (int j = 0; j < 4; j++) acc[i][j] = (f32x4){0.f, 0.f, 0.f, 0.f};

  const int lane_row = lane >> 3;            // 0..7 within chunk
  const int lane_col = (lane & 7) * 8;       // bf16 col offset (16B granules)

  for (int kt = 0; kt < 64; kt++) {
    const int kofs = kt * 64;
    __syncthreads();
    #pragma unroll
    for (int c = 0; c < 4; c++) {
      const int chunk = wave * 4 + c;                  // 0..15
      const int row = chunk * 8 + lane_row;            // 0..127
      GLD16(A  + (m0 + row) * 4096 + kofs + lane_col, &As[chunk * 512 + lane * 8]);
      GLD16(Bm + (n0 + row) * 4096 + kofs + lane_col, &Bs[chunk * 512 + lane * 8]);
    }
    __syncthreads();

    #pragma unroll
    for (int ks = 0; ks < 2; ks++) {
      const int k0 = ks * 32;
      bf16x8 a[4], b[4];
      #pragma unroll
      for (int i = 0; i < 4; i++)
        a[i] = *(const bf16x8*)&As[(wm + i * 16 + l16) * 64 + k0 + quad * 8];
      #pragma unroll
      for (int j = 0; j < 4; j++)
        b[j] = *(const bf16x8*)&Bs[(wn + j * 16 + l16) * 64 + k0 + quad * 8];
      #pragma unroll
      for (int i = 0; i < 4; i++)
        #pragma unroll
        for (int j = 0; j < 4; j++)
          acc[i][j] = __builtin_amdgcn_mfma_f32_16x16x32_bf16(a[i], b[j], acc[i][j], 0, 0, 0);
    }
  }

  // epilogue: C/D layout col=lane&15, row=quad*4+reg
  #pragma unroll
  for (int i = 0; i < 4; i++) {
    #pragma unroll
    for (int r = 0; r < 4; r++) {
      const int brow = m0 + wm + i * 16 + quad * 4 + r;
      float* crow = C + brow * 8192 + n0 + wn + l16;
      #pragma unroll
      for (int j = 0; j < 4; j++) crow[j * 16] = acc[i][j][r];
    }
  }
}

// ---------------- k4: row-normalize d_out (1024 rows of 8192) ----------------
__global__ __launch_bounds__(256) void norm_kernel(float* __restrict__ out) {
  const int b = blockIdx.x;
  const int t = threadIdx.x;
  const int lane = t & 63, wave = t >> 6;
  __shared__ float red[4];

  float4* row = (float4*)(out + b * 8192);   // 2048 float4
  float4 v[8];
  float s = 0.0f;
  #pragma unroll
  for (int q = 0; q < 8; q++) {
    v[q] = row[q * 256 + t];
    s += (v[q].x + v[q].y) + (v[q].z + v[q].w);
  }
  float ws = wave_sum(s);
  if (lane == 0) red[wave] = ws;
  __syncthreads();
  float tot = (red[0] + red[1]) + (red[2] + red[3]);
  float inv = 1.0f / tot;
  #pragma unroll
  for (int q = 0; q < 8; q++) {
    v[q].x *= inv; v[q].y *= inv; v[q].z *= inv; v[q].w *= inv;
    row[q * 256 + t] = v[q];
  }
}

// ---------------------------------------------------------------------------
extern "C" void kernel_launch(void* const* d_in, const int* in_sizes, int n_in,
                              void* d_out, int out_size, void* d_ws, size_t ws_size,
                              hipStream_t stream) {
  const float* freq    = (const float*)d_in[0];   // 1024*4096
  const float* kparams = (const float*)d_in[1];   // 8192*4*6
  const float* temp    = (const float*)d_in[2];   // 1
  // d_in[3] = kmer_idcs (recomputed analytically in-kernel)

  float* out = (float*)d_out;                     // 1024*8192

  short* probs = (short*)d_ws;                    // 8192*4096 bf16 = 64 MiB
  short* freqb = probs + (size_t)8192 * 4096;     // 1024*4096 bf16 = 8 MiB

  cast_kernel <<<4096, 256, 0, stream>>>(freq, freqb);
  probs_kernel<<<8192, 256, 0, stream>>>(kparams, temp, probs);
  gemm_kernel <<<dim3(64, 8), 256, 0, stream>>>(freqb, probs, out);
  norm_kernel <<<1024, 256, 0, stream>>>(out);
}

// Round 3
// 182.186 us; speedup vs baseline: 1.0874x; 1.0874x over previous
//
#include <hip/hip_runtime.h>

// ---------------------------------------------------------------------------
// ConvFeatureExtractor: profile = rownorm( freq @ softmax(matches/T, axis=1)^T )
//   matches[f,i] = sum_j kmer_params[f, digit_j(i), j],  F=8192, M=4096, B=1024, K=6
// R3: (a) XOR-swizzled LDS tiles in GEMM to kill the 32-bank row-stride
//         conflicts (row stride 128B == 32 banks; swizzle col-block by row&7).
//     (b) probs_kernel: contiguous-16 per thread + 16B vector stores.
// ---------------------------------------------------------------------------

typedef __bf16  bf16x8 __attribute__((ext_vector_type(8)));
typedef float   f32x4  __attribute__((ext_vector_type(4)));
typedef short   short8v __attribute__((ext_vector_type(8)));

#define GLD16(gp, lp)                                                          \
  __builtin_amdgcn_global_load_lds(                                            \
      (const __attribute__((address_space(1))) void*)(gp),                     \
      (__attribute__((address_space(3))) void*)(lp), 16, 0, 0)

__device__ __forceinline__ short f2bf(float x) {
  unsigned u = __float_as_uint(x);
  unsigned r = (u + 0x7fffu + ((u >> 16) & 1u)) >> 16;   // RNE
  return (short)r;
}

__device__ __forceinline__ float wave_max(float v) {
  #pragma unroll
  for (int off = 32; off; off >>= 1) v = fmaxf(v, __shfl_xor(v, off, 64));
  return v;
}
__device__ __forceinline__ float wave_sum(float v) {
  #pragma unroll
  for (int off = 32; off; off >>= 1) v += __shfl_xor(v, off, 64);
  return v;
}

// ---------------- k1: freq f32 -> bf16 ----------------
__global__ __launch_bounds__(256) void cast_kernel(const float* __restrict__ in,
                                                   short* __restrict__ out) {
  int idx = blockIdx.x * 256 + threadIdx.x;      // 4 floats each
  float4 v = ((const float4*)in)[idx];
  short4 o;
  o.x = f2bf(v.x); o.y = f2bf(v.y); o.z = f2bf(v.z); o.w = f2bf(v.w);
  ((short4*)out)[idx] = o;
}

// ---------------- k2: matches + softmax -> probs bf16 ----------------
// grid = 8192 (one block per filter), block = 256; thread t owns kmers
// [t*16, t*16+16) which share a single Thi entry (t>>2).
__global__ __launch_bounds__(256) void probs_kernel(const float* __restrict__ kp,
                                                    const float* __restrict__ temp,
                                                    short* __restrict__ probs) {
  const int f = blockIdx.x;
  const int t = threadIdx.x;
  const int lane = t & 63, wave = t >> 6;

  __shared__ float P[24];          // kmer_params[f] : [4][6]
  __shared__ float Thi[64], Tlo[64];
  __shared__ float redA[4], redB[4];

  if (t < 24) P[t] = kp[f * 24 + t];
  __syncthreads();
  if (t < 64) {
    // digits most-significant first: Thi covers j=0,1,2 ; Tlo covers j=3,4,5
    Thi[t] = P[((t >> 4) & 3) * 6 + 0] + P[((t >> 2) & 3) * 6 + 1] + P[(t & 3) * 6 + 2];
    Tlo[t] = P[((t >> 4) & 3) * 6 + 3] + P[((t >> 2) & 3) * 6 + 4] + P[(t & 3) * 6 + 5];
  }
  __syncthreads();

  const float hi = Thi[t >> 2];
  const int lo0 = (t & 3) * 16;
  float m[16];
  float mx = -1e30f;
  #pragma unroll
  for (int s = 0; s < 16; s++) {
    m[s] = hi + Tlo[lo0 + s];
    mx = fmaxf(mx, m[s]);
  }
  float wmx = wave_max(mx);
  if (lane == 0) redA[wave] = wmx;
  __syncthreads();
  mx = fmaxf(fmaxf(redA[0], redA[1]), fmaxf(redA[2], redA[3]));

  const float invT = 1.0f / temp[0];
  float e[16];
  float lsum = 0.0f;
  #pragma unroll
  for (int s = 0; s < 16; s++) {
    e[s] = __expf((m[s] - mx) * invT);
    lsum += e[s];
  }
  float wsum = wave_sum(lsum);
  if (lane == 0) redB[wave] = wsum;
  __syncthreads();
  float tot = (redB[0] + redB[1]) + (redB[2] + redB[3]);
  float inv = 1.0f / tot;

  short8v* prow = (short8v*)(probs + (size_t)f * 4096 + t * 16);
  short8v o0, o1;
  #pragma unroll
  for (int s = 0; s < 8; s++) { o0[s] = f2bf(e[s] * inv); o1[s] = f2bf(e[s + 8] * inv); }
  prow[0] = o0;
  prow[1] = o1;
}

// ---------------- k3: GEMM pooled = A(1024x4096) * B(8192x4096)^T ----------------
// C row-major 1024x8192 fp32. Tiles: TM=128 (batch), TN=128 (filters), BK=64.
// 256 threads = 4 waves in 2x2; each wave does 64x64 via 4x4 of 16x16x32 mfma.
// LDS tiles are XOR-swizzled: physical col-block p (16B units) at row r holds
// logical col-block p ^ (r&7). Staging loads global col (p^(r&7))*8 into
// physical slot p; readers address physical (qq ^ (row&7)).
__global__ __launch_bounds__(256) void gemm_kernel(const short* __restrict__ A,
                                                   const short* __restrict__ Bm,
                                                   float* __restrict__ C) {
  __shared__ short As[128 * 64];
  __shared__ short Bs[128 * 64];

  const int t = threadIdx.x;
  const int lane = t & 63, wave = t >> 6;
  const int quad = lane >> 4, l16 = lane & 15;
  const int m0 = blockIdx.y * 128;       // batch tile
  const int n0 = blockIdx.x * 128;       // filter tile
  const int wm = (wave & 1) * 64, wn = (wave >> 1) * 64;

  f32x4 acc[4][4];
  #pragma unroll
  for (int i = 0; i < 4; i++)
    #pragma unroll
    for (int j = 0; j < 4; j++) acc[i][j] = (f32x4){0.f, 0.f, 0.f, 0.f};

  const int lane_row = lane >> 3;                      // 0..7 within chunk
  const int src_col = ((lane & 7) ^ lane_row) * 8;     // swizzled global col (shorts)
  const int sw = l16 & 7;                              // reader swizzle key (= row&7)

  for (int kt = 0; kt < 64; kt++) {
    const int kofs = kt * 64;
    __syncthreads();
    #pragma unroll
    for (int c = 0; c < 4; c++) {
      const int chunk = wave * 4 + c;                  // 0..15
      const int row = chunk * 8 + lane_row;            // 0..127
      GLD16(A  + (m0 + row) * 4096 + kofs + src_col, &As[chunk * 512 + lane * 8]);
      GLD16(Bm + (n0 + row) * 4096 + kofs + src_col, &Bs[chunk * 512 + lane * 8]);
    }
    __syncthreads();

    #pragma unroll
    for (int ks = 0; ks < 2; ks++) {
      const int pcol = ((ks * 4 + quad) ^ sw) * 8;     // physical col (shorts)
      bf16x8 a[4], b[4];
      #pragma unroll
      for (int i = 0; i < 4; i++)
        a[i] = *(const bf16x8*)&As[(wm + i * 16 + l16) * 64 + pcol];
      #pragma unroll
      for (int j = 0; j < 4; j++)
        b[j] = *(const bf16x8*)&Bs[(wn + j * 16 + l16) * 64 + pcol];
      #pragma unroll
      for (int i = 0; i < 4; i++)
        #pragma unroll
        for (int j = 0; j < 4; j++)
          acc[i][j] = __builtin_amdgcn_mfma_f32_16x16x32_bf16(a[i], b[j], acc[i][j], 0, 0, 0);
    }
  }

  // epilogue: C/D layout col=lane&15, row=quad*4+reg
  #pragma unroll
  for (int i = 0; i < 4; i++) {
    #pragma unroll
    for (int r = 0; r < 4; r++) {
      const int brow = m0 + wm + i * 16 + quad * 4 + r;
      float* crow = C + brow * 8192 + n0 + wn + l16;
      #pragma unroll
      for (int j = 0; j < 4; j++) crow[j * 16] = acc[i][j][r];
    }
  }
}

// ---------------- k4: row-normalize d_out (1024 rows of 8192) ----------------
__global__ __launch_bounds__(256) void norm_kernel(float* __restrict__ out) {
  const int b = blockIdx.x;
  const int t = threadIdx.x;
  const int lane = t & 63, wave = t >> 6;
  __shared__ float red[4];

  float4* row = (float4*)(out + b * 8192);   // 2048 float4
  float4 v[8];
  float s = 0.0f;
  #pragma unroll
  for (int q = 0; q < 8; q++) {
    v[q] = row[q * 256 + t];
    s += (v[q].x + v[q].y) + (v[q].z + v[q].w);
  }
  float ws = wave_sum(s);
  if (lane == 0) red[wave] = ws;
  __syncthreads();
  float tot = (red[0] + red[1]) + (red[2] + red[3]);
  float inv = 1.0f / tot;
  #pragma unroll
  for (int q = 0; q < 8; q++) {
    v[q].x *= inv; v[q].y *= inv; v[q].z *= inv; v[q].w *= inv;
    row[q * 256 + t] = v[q];
  }
}

// ---------------------------------------------------------------------------
extern "C" void kernel_launch(void* const* d_in, const int* in_sizes, int n_in,
                              void* d_out, int out_size, void* d_ws, size_t ws_size,
                              hipStream_t stream) {
  const float* freq    = (const float*)d_in[0];   // 1024*4096
  const float* kparams = (const float*)d_in[1];   // 8192*4*6
  const float* temp    = (const float*)d_in[2];   // 1
  // d_in[3] = kmer_idcs (recomputed analytically in-kernel)

  float* out = (float*)d_out;                     // 1024*8192

  short* probs = (short*)d_ws;                    // 8192*4096 bf16 = 64 MiB
  short* freqb = probs + (size_t)8192 * 4096;     // 1024*4096 bf16 = 8 MiB

  cast_kernel <<<4096, 256, 0, stream>>>(freq, freqb);
  probs_kernel<<<8192, 256, 0, stream>>>(kparams, temp, probs);
  gemm_kernel <<<dim3(64, 8), 256, 0, stream>>>(freqb, probs, out);
  norm_kernel <<<1024, 256, 0, stream>>>(out);
}